// Round 2
// baseline (1185.022 us; speedup 1.0000x reference)
//
#include <hip/hip_runtime.h>
#include <hip/hip_bf16.h>
#include <stdint.h>

#define Bsz  2
#define Tseq 2048
#define Dmod 1024
#define Hn   16
#define DHd  64

typedef short bf16x8 __attribute__((ext_vector_type(8)));
typedef float f32x4 __attribute__((ext_vector_type(4)));

__device__ __forceinline__ float bf2f(unsigned short u) {
  union { unsigned int i; float f; } v; v.i = ((unsigned int)u) << 16; return v.f;
}
__device__ __forceinline__ unsigned short f2bf(float f) {
  union { float f; unsigned int i; } v; v.f = f;
  unsigned int r = (v.i + 0x7fffu + ((v.i >> 16) & 1u)) >> 16;
  return (unsigned short)r;
}
__device__ __forceinline__ float2 unpack2(unsigned int u) {
  union { unsigned int i; float f; } a, b;
  a.i = u << 16; b.i = u & 0xffff0000u;
  float2 r; r.x = a.f; r.y = b.f; return r;
}

// ---------------- cast fp32 -> bf16, 8 elems/thread ----------------
__global__ __launch_bounds__(256) void cast_f32_bf16(const float* __restrict__ in,
                                                     unsigned short* __restrict__ out,
                                                     int n) {
  int idx = (blockIdx.x * 256 + threadIdx.x) * 8;
  if (idx + 8 > n) return;
  float4 a = *(const float4*)&in[idx];
  float4 b = *(const float4*)&in[idx + 4];
  unsigned short o[8];
  o[0] = f2bf(a.x); o[1] = f2bf(a.y); o[2] = f2bf(a.z); o[3] = f2bf(a.w);
  o[4] = f2bf(b.x); o[5] = f2bf(b.y); o[6] = f2bf(b.z); o[7] = f2bf(b.w);
  *(uint4*)&out[idx] = *(const uint4*)o;
}

// ---------------- transpose+cast: in fp32 [K][N] -> out bf16 [N][K] ----------------
__global__ __launch_bounds__(256) void transpose_cast(const float* __restrict__ in,
                                                      unsigned short* __restrict__ out,
                                                      int K, int N) {
  __shared__ unsigned short tile[64][65];
  const int k0 = blockIdx.y * 64, n0 = blockIdx.x * 64;
  for (int i = threadIdx.x; i < 4096; i += 256) {
    int r = i >> 6, c = i & 63;
    tile[r][c] = f2bf(in[(size_t)(k0 + r) * N + n0 + c]);
  }
  __syncthreads();
  for (int i = threadIdx.x; i < 4096; i += 256) {
    int r = i >> 6, c = i & 63;
    out[(size_t)(n0 + r) * K + k0 + c] = tile[c][r];
  }
}

// ---------------- GEMM: C[m][n] = sum_k A[m][k]*Bt[n][k] + bias[n] ----------------
// 128x128 tile / block (256 thr = 4 waves, each wave 64x64 via 4x4 MFMA 16x16x32)
// mode 0: scatter bf16 to Q/K/V [B,H,T,DH]; mode 1: write fp32 outF[m*N+n]
__global__ __launch_bounds__(256) void gemm_bt(const unsigned short* __restrict__ A,
                                               const unsigned short* __restrict__ Bt,
                                               const float* __restrict__ bias,
                                               int M, int N, int K, int mode,
                                               float* __restrict__ outF,
                                               unsigned short* __restrict__ out0,
                                               unsigned short* __restrict__ out1,
                                               unsigned short* __restrict__ out2) {
  __shared__ unsigned short As[128 * 64];
  __shared__ unsigned short Bs[128 * 64];
  const int tid  = threadIdx.x;
  const int lane = tid & 63;
  const int w    = tid >> 6;
  const int m0   = blockIdx.x * 128;
  const int n0   = blockIdx.y * 128;
  const int wr   = (w >> 1) * 64;
  const int wc   = (w & 1) * 64;

  f32x4 acc[4][4];
  for (int i = 0; i < 4; i++)
    for (int j = 0; j < 4; j++)
      for (int v = 0; v < 4; v++) acc[i][j][v] = 0.0f;

  const int sr = tid >> 3;        // 0..31 staging row
  const int sc = (tid & 7) * 8;   // bf16 col start (16B units)
  const int l16 = lane & 15;
  const int q8  = (lane >> 4) * 8;

  for (int kt = 0; kt < K; kt += 64) {
    __syncthreads();
#pragma unroll
    for (int p = 0; p < 4; p++) {
      int r = sr + 32 * p;
      *(uint4*)&As[r * 64 + sc] = *(const uint4*)&A[(size_t)(m0 + r) * K + kt + sc];
      *(uint4*)&Bs[r * 64 + sc] = *(const uint4*)&Bt[(size_t)(n0 + r) * K + kt + sc];
    }
    __syncthreads();
#pragma unroll
    for (int ks = 0; ks < 2; ks++) {
      bf16x8 af[4], bf[4];
#pragma unroll
      for (int i = 0; i < 4; i++)
        af[i] = *(const bf16x8*)&As[(wr + i * 16 + l16) * 64 + ks * 32 + q8];
#pragma unroll
      for (int j = 0; j < 4; j++)
        bf[j] = *(const bf16x8*)&Bs[(wc + j * 16 + l16) * 64 + ks * 32 + q8];
#pragma unroll
      for (int i = 0; i < 4; i++)
#pragma unroll
        for (int j = 0; j < 4; j++)
          acc[i][j] = __builtin_amdgcn_mfma_f32_16x16x32_bf16(af[i], bf[j], acc[i][j], 0, 0, 0);
    }
  }

  const int q4 = (lane >> 4) * 4;
#pragma unroll
  for (int i = 0; i < 4; i++)
#pragma unroll
    for (int j = 0; j < 4; j++)
#pragma unroll
      for (int v = 0; v < 4; v++) {
        int m = m0 + wr + i * 16 + q4 + v;
        int n = n0 + wc + j * 16 + l16;
        float val = acc[i][j][v] + bias[n];
        if (mode == 0) {
          int which = n >> 10;
          int rem = n & 1023;
          int h = rem >> 6, dd = rem & 63;
          int b = m >> 11, t = m & 2047;
          unsigned short* dst = (which == 0) ? out0 : ((which == 1) ? out1 : out2);
          dst[(size_t)((b * Hn + h) * Tseq + t) * DHd + dd] = f2bf(val);
        } else {
          outF[(size_t)m * N + n] = val;
        }
      }
}

// ---------------- causal attention, scalar flash ----------------
// grid (T/64, B*H); block 256 = 4 waves; wave w owns q-rows w*16..w*16+15 of the tile
__global__ __launch_bounds__(256) void attn(const unsigned short* __restrict__ Qb,
                                            const unsigned short* __restrict__ Kb,
                                            const unsigned short* __restrict__ Vb,
                                            unsigned short* __restrict__ O) {
  __shared__ unsigned short Qs[64 * 64];
  __shared__ unsigned short Ks[64 * 66];   // [k-row][d], stride 66 (2-way banks, free)
  __shared__ unsigned short Vs[64 * 66];
  __shared__ float Pst[64 * 68];           // [j][q-row], stride 68 (16B-aligned rows)

  const int tid  = threadIdx.x;
  const int lane = tid & 63;
  const int w    = tid >> 6;
  const int qt   = blockIdx.x;
  const int bh   = blockIdx.y;
  const int b    = bh >> 4;
  const int h    = bh & 15;

  const size_t base = (size_t)bh * Tseq * DHd;
  const unsigned short* q = Qb + base + (size_t)qt * 64 * DHd;
  const unsigned short* k = Kb + base;
  const unsigned short* v = Vb + base;

  const int sr = tid >> 3;        // 0..31
  const int sc = (tid & 7) * 8;

  // stage Q tile (64x64)
#pragma unroll
  for (int p = 0; p < 2; p++) {
    int r = sr + 32 * p;
    *(uint4*)&Qs[r * 64 + sc] = *(const uint4*)&q[r * 64 + sc];
  }

  float mreg[16], lreg[16], acc[16];
#pragma unroll
  for (int r = 0; r < 16; r++) { mreg[r] = -1e30f; lreg[r] = 0.f; acc[r] = 0.f; }

  const int nch = qt + 1;
  for (int c = 0; c < nch; c++) {
    __syncthreads();  // previous chunk fully consumed
#pragma unroll
    for (int p = 0; p < 2; p++) {
      int r = sr + 32 * p;
      uint4 kk = *(const uint4*)&k[(size_t)(c * 64 + r) * DHd + sc];
      uint4 vv = *(const uint4*)&v[(size_t)(c * 64 + r) * DHd + sc];
      unsigned int* kd = (unsigned int*)&Ks[r * 66 + sc];
      unsigned int* vd = (unsigned int*)&Vs[r * 66 + sc];
      kd[0] = kk.x; kd[1] = kk.y; kd[2] = kk.z; kd[3] = kk.w;
      vd[0] = vv.x; vd[1] = vv.y; vd[2] = vv.z; vd[3] = vv.w;
    }
    __syncthreads();

    // phase 1: scores, lanes over k (lane = k index within chunk)
    float sreg[16];
#pragma unroll
    for (int r = 0; r < 16; r++) sreg[r] = 0.f;
    const unsigned int* krow  = (const unsigned int*)&Ks[lane * 66];
    const unsigned int* qbase = (const unsigned int*)&Qs[(w * 16) * 64];
    for (int d2 = 0; d2 < 32; d2++) {
      float2 kv = unpack2(krow[d2]);
#pragma unroll
      for (int r = 0; r < 16; r++) {
        float2 qv = unpack2(qbase[r * 32 + d2]);
        sreg[r] += qv.x * kv.x + qv.y * kv.y;
      }
    }

    // softmax update per row
#pragma unroll
    for (int r = 0; r < 16; r++) {
      const int row = w * 16 + r;
      const int tq  = qt * 64 + row;
      float s = sreg[r] * 0.125f;
      if (c * 64 + lane > tq) s = -1e30f;
      float smax = s;
#pragma unroll
      for (int off = 32; off; off >>= 1) smax = fmaxf(smax, __shfl_xor(smax, off));
      float mn = fmaxf(mreg[r], smax);
      float p = __expf(s - mn);
      float alpha = __expf(mreg[r] - mn);
      float ps = p;
#pragma unroll
      for (int off = 32; off; off >>= 1) ps += __shfl_xor(ps, off);
      lreg[r] = lreg[r] * alpha + ps;
      mreg[r] = mn;
      acc[r] *= alpha;
      Pst[lane * 68 + row] = p;   // wave-local columns, same-wave LDS is ordered
    }

    // phase 2: acc[d=lane] += sum_j p[row][j] * V[j][d]
    for (int j = 0; j < 64; j++) {
      float vj = bf2f(Vs[j * 66 + lane]);
      const float* pr = &Pst[j * 68 + w * 16];
      float4 p0 = *(const float4*)(pr);
      float4 p1 = *(const float4*)(pr + 4);
      float4 p2 = *(const float4*)(pr + 8);
      float4 p3 = *(const float4*)(pr + 12);
      acc[0]  += p0.x * vj; acc[1]  += p0.y * vj; acc[2]  += p0.z * vj; acc[3]  += p0.w * vj;
      acc[4]  += p1.x * vj; acc[5]  += p1.y * vj; acc[6]  += p1.z * vj; acc[7]  += p1.w * vj;
      acc[8]  += p2.x * vj; acc[9]  += p2.y * vj; acc[10] += p2.z * vj; acc[11] += p2.w * vj;
      acc[12] += p3.x * vj; acc[13] += p3.y * vj; acc[14] += p3.z * vj; acc[15] += p3.w * vj;
    }
  }

  // write O[b][t][h*64 + d], bf16
#pragma unroll
  for (int r = 0; r < 16; r++) {
    const int tq = qt * 64 + w * 16 + r;
    float o = acc[r] / lreg[r];
    O[((size_t)(b * Tseq + tq)) * Dmod + h * DHd + lane] = f2bf(o);
  }
}

extern "C" void kernel_launch(void* const* d_in, const int* in_sizes, int n_in,
                              void* d_out, int out_size, void* d_ws, size_t ws_size,
                              hipStream_t stream) {
  (void)in_sizes; (void)n_in; (void)out_size; (void)ws_size;
  const float* x     = (const float*)d_in[0];  // [B,T,D]   fp32
  const float* w_qkv = (const float*)d_in[1];  // [D,3D]    fp32
  const float* b_qkv = (const float*)d_in[2];  // [3D]      fp32
  const float* w_out = (const float*)d_in[3];  // [D,D]     fp32
  const float* b_out = (const float*)d_in[4];  // [D]       fp32
  float* out = (float*)d_out;                  // [B,T,D]   fp32

  unsigned short* ws    = (unsigned short*)d_ws;
  unsigned short* xb    = ws;                            // [B*T, D] bf16, reused as Ob
  unsigned short* wqkvT = xb    + (size_t)4194304;       // [3D][D]
  unsigned short* woutT = wqkvT + (size_t)3072 * 1024;   // [D][D]
  unsigned short* Qb    = woutT + (size_t)1024 * 1024;   // [B,H,T,DH]
  unsigned short* Kb    = Qb + (size_t)4194304;
  unsigned short* Vb    = Kb + (size_t)4194304;
  unsigned short* Ob    = xb;  // reuse: xb dead after GEMM1
  // total ws use: 20M bf16 = 40 MB

  cast_f32_bf16<<<2048, 256, 0, stream>>>(x, xb, 4194304);
  transpose_cast<<<dim3(48, 16), 256, 0, stream>>>(w_qkv, wqkvT, 1024, 3072);
  transpose_cast<<<dim3(16, 16), 256, 0, stream>>>(w_out, woutT, 1024, 1024);
  gemm_bt<<<dim3(32, 24), 256, 0, stream>>>(xb, wqkvT, b_qkv, 4096, 3072, 1024, 0,
                                            nullptr, Qb, Kb, Vb);
  attn<<<dim3(32, 32), 256, 0, stream>>>(Qb, Kb, Vb, Ob);
  gemm_bt<<<dim3(32, 8), 256, 0, stream>>>(Ob, woutT, b_out, 4096, 1024, 1024, 1,
                                           out, nullptr, nullptr, nullptr);
}

// Round 3
// 257.104 us; speedup vs baseline: 4.6091x; 4.6091x over previous
//
#include <hip/hip_runtime.h>
#include <hip/hip_bf16.h>
#include <stdint.h>

#define Bsz  2
#define Tseq 2048
#define Dmod 1024
#define Hn   16
#define DHd  64

typedef short bf16x8 __attribute__((ext_vector_type(8)));
typedef float f32x4 __attribute__((ext_vector_type(4)));

__device__ __forceinline__ float bf2f(unsigned short u) {
  union { unsigned int i; float f; } v; v.i = ((unsigned int)u) << 16; return v.f;
}
__device__ __forceinline__ unsigned short f2bf(float f) {
  union { float f; unsigned int i; } v; v.f = f;
  unsigned int r = (v.i + 0x7fffu + ((v.i >> 16) & 1u)) >> 16;
  return (unsigned short)r;
}

// ---------------- cast fp32 -> bf16, 8 elems/thread ----------------
__global__ __launch_bounds__(256) void cast_f32_bf16(const float* __restrict__ in,
                                                     unsigned short* __restrict__ out,
                                                     int n) {
  int idx = (blockIdx.x * 256 + threadIdx.x) * 8;
  if (idx + 8 > n) return;
  float4 a = *(const float4*)&in[idx];
  float4 b = *(const float4*)&in[idx + 4];
  unsigned short o[8];
  o[0] = f2bf(a.x); o[1] = f2bf(a.y); o[2] = f2bf(a.z); o[3] = f2bf(a.w);
  o[4] = f2bf(b.x); o[5] = f2bf(b.y); o[6] = f2bf(b.z); o[7] = f2bf(b.w);
  *(uint4*)&out[idx] = *(const uint4*)o;
}

// ---------------- transpose+cast: in fp32 [K][N] -> out bf16 [N][K] ----------------
__global__ __launch_bounds__(256) void transpose_cast(const float* __restrict__ in,
                                                      unsigned short* __restrict__ out,
                                                      int K, int N) {
  __shared__ unsigned short tile[64][65];
  const int k0 = blockIdx.y * 64, n0 = blockIdx.x * 64;
  for (int i = threadIdx.x; i < 4096; i += 256) {
    int r = i >> 6, c = i & 63;
    tile[r][c] = f2bf(in[(size_t)(k0 + r) * N + n0 + c]);
  }
  __syncthreads();
  for (int i = threadIdx.x; i < 4096; i += 256) {
    int r = i >> 6, c = i & 63;
    out[(size_t)(n0 + r) * K + k0 + c] = tile[c][r];
  }
}

// ---------------- GEMM: C[m][n] = sum_k A[m][k]*Bt[n][k] + bias[n] ----------------
// mode 0: scatter bf16 to Q [B,H,T,DH] / K [B,H,T,DH] / V transposed [B,H,DH,T]
// mode 1: write fp32 outF[m*N+n]
__global__ __launch_bounds__(256) void gemm_bt(const unsigned short* __restrict__ A,
                                               const unsigned short* __restrict__ Bt,
                                               const float* __restrict__ bias,
                                               int M, int N, int K, int mode,
                                               float* __restrict__ outF,
                                               unsigned short* __restrict__ out0,
                                               unsigned short* __restrict__ out1,
                                               unsigned short* __restrict__ out2) {
  __shared__ unsigned short As[128 * 64];
  __shared__ unsigned short Bs[128 * 64];
  const int tid  = threadIdx.x;
  const int lane = tid & 63;
  const int w    = tid >> 6;
  const int m0   = blockIdx.x * 128;
  const int n0   = blockIdx.y * 128;
  const int wr   = (w >> 1) * 64;
  const int wc   = (w & 1) * 64;

  f32x4 acc[4][4];
  for (int i = 0; i < 4; i++)
    for (int j = 0; j < 4; j++)
      for (int v = 0; v < 4; v++) acc[i][j][v] = 0.0f;

  const int sr = tid >> 3;
  const int sc = (tid & 7) * 8;
  const int l16 = lane & 15;
  const int q8  = (lane >> 4) * 8;

  for (int kt = 0; kt < K; kt += 64) {
    __syncthreads();
#pragma unroll
    for (int p = 0; p < 4; p++) {
      int r = sr + 32 * p;
      *(uint4*)&As[r * 64 + sc] = *(const uint4*)&A[(size_t)(m0 + r) * K + kt + sc];
      *(uint4*)&Bs[r * 64 + sc] = *(const uint4*)&Bt[(size_t)(n0 + r) * K + kt + sc];
    }
    __syncthreads();
#pragma unroll
    for (int ks = 0; ks < 2; ks++) {
      bf16x8 af[4], bf[4];
#pragma unroll
      for (int i = 0; i < 4; i++)
        af[i] = *(const bf16x8*)&As[(wr + i * 16 + l16) * 64 + ks * 32 + q8];
#pragma unroll
      for (int j = 0; j < 4; j++)
        bf[j] = *(const bf16x8*)&Bs[(wc + j * 16 + l16) * 64 + ks * 32 + q8];
#pragma unroll
      for (int i = 0; i < 4; i++)
#pragma unroll
        for (int j = 0; j < 4; j++)
          acc[i][j] = __builtin_amdgcn_mfma_f32_16x16x32_bf16(af[i], bf[j], acc[i][j], 0, 0, 0);
    }
  }

  const int q4 = (lane >> 4) * 4;
#pragma unroll
  for (int i = 0; i < 4; i++)
#pragma unroll
    for (int j = 0; j < 4; j++)
#pragma unroll
      for (int v = 0; v < 4; v++) {
        int m = m0 + wr + i * 16 + q4 + v;
        int n = n0 + wc + j * 16 + l16;
        float val = acc[i][j][v] + bias[n];
        if (mode == 0) {
          int which = n >> 10;
          int rem = n & 1023;
          int h = rem >> 6, dd = rem & 63;
          int b = m >> 11, t = m & 2047;
          if (which == 0)
            out0[(size_t)((b * Hn + h) * Tseq + t) * DHd + dd] = f2bf(val);
          else if (which == 1)
            out1[(size_t)((b * Hn + h) * Tseq + t) * DHd + dd] = f2bf(val);
          else  // V stored transposed: [b,h][dd][t]
            out2[((size_t)((b * Hn + h) * DHd + dd)) * Tseq + t] = f2bf(val);
        } else {
          outF[(size_t)m * N + n] = val;
        }
      }
}

// ---------------- MFMA causal flash attention ----------------
// grid (T/128, B*H); block 256 = 4 waves; wave w owns q-rows [q0b+32w, q0b+32w+32)
// S^T = MFMA(A=K, B=Q): C col=q (lane&15), row=j ((lane>>4)*4+v)
// P^T packed to LDS [q][j] (b64 writes), PV = MFMA(A=P, B=V^T from Vs[d][j])
__global__ __launch_bounds__(256, 3) void attn_mfma(const unsigned short* __restrict__ Qb,
                                                    const unsigned short* __restrict__ Kb,
                                                    const unsigned short* __restrict__ Vtg,
                                                    unsigned short* __restrict__ O) {
  __shared__ unsigned short Ks[64 * 72];       // [j][d]
  __shared__ unsigned short Vs[64 * 72];       // [d][j]
  __shared__ unsigned short Ps[4 * 32 * 72];   // per-wave [q][j]
  __shared__ float als[4][32];
  __shared__ float lls[4][32];

  const int tid  = threadIdx.x;
  const int lane = tid & 63;
  const int w    = tid >> 6;
  const int g    = lane >> 4;
  const int l16  = lane & 15;
  const int qblk = gridDim.x - 1 - blockIdx.x;   // heavy blocks first
  const int bh   = blockIdx.y;
  const int q0b  = qblk * 128;
  const int q0w  = q0b + w * 32;

  const unsigned short* Qp = Qb  + (size_t)bh * Tseq * DHd;
  const unsigned short* Kp = Kb  + (size_t)bh * Tseq * DHd;
  const unsigned short* Vp = Vtg + (size_t)bh * DHd * Tseq;

  // Q B-fragments direct from global: n=q (lane&15), k=d ((lane>>4)*8+..)
  bf16x8 qf[2][2];
#pragma unroll
  for (int qt = 0; qt < 2; qt++)
#pragma unroll
    for (int ks = 0; ks < 2; ks++)
      qf[qt][ks] = *(const bf16x8*)&Qp[(size_t)(q0w + 16 * qt + l16) * DHd + ks * 32 + g * 8];

  f32x4 Oacc[2][4];
#pragma unroll
  for (int qt = 0; qt < 2; qt++)
#pragma unroll
    for (int dt = 0; dt < 4; dt++)
#pragma unroll
      for (int v = 0; v < 4; v++) Oacc[qt][dt][v] = 0.f;

  float mrow[2] = {-1e30f, -1e30f};
  float lrow[2] = {0.f, 0.f};
  unsigned short* Pw = &Ps[w * 32 * 72];

  const int nch = 2 * qblk + 2;
  for (int c = 0; c < nch; c++) {
    __syncthreads();
#pragma unroll
    for (int i = 0; i < 2; i++) {
      int e = tid + 256 * i;
      int row = e >> 3, gg = e & 7;
      *(uint4*)&Ks[row * 72 + gg * 8] = *(const uint4*)&Kp[(size_t)(c * 64 + row) * DHd + gg * 8];
      *(uint4*)&Vs[row * 72 + gg * 8] = *(const uint4*)&Vp[(size_t)row * Tseq + c * 64 + gg * 8];
    }
    __syncthreads();
    if (c * 64 > q0w + 31) continue;   // wave fully above diagonal: staging+barriers only

    // S^T tiles: st[mt(j)][qt]
    f32x4 st[4][2];
#pragma unroll
    for (int mt = 0; mt < 4; mt++)
#pragma unroll
      for (int qt = 0; qt < 2; qt++)
#pragma unroll
        for (int v = 0; v < 4; v++) st[mt][qt][v] = 0.f;

#pragma unroll
    for (int ks = 0; ks < 2; ks++) {
      bf16x8 kf[4];
#pragma unroll
      for (int mt = 0; mt < 4; mt++)
        kf[mt] = *(const bf16x8*)&Ks[(16 * mt + l16) * 72 + ks * 32 + g * 8];
#pragma unroll
      for (int mt = 0; mt < 4; mt++)
#pragma unroll
        for (int qt = 0; qt < 2; qt++)
          st[mt][qt] = __builtin_amdgcn_mfma_f32_16x16x32_bf16(kf[mt], qf[qt][ks], st[mt][qt], 0, 0, 0);
    }

    const bool domask = (c >= 2 * qblk);
#pragma unroll
    for (int qt = 0; qt < 2; qt++) {
      const int qg = q0w + 16 * qt + l16;
      float mx = -1e30f;
#pragma unroll
      for (int mt = 0; mt < 4; mt++)
#pragma unroll
        for (int v = 0; v < 4; v++) {
          float s = st[mt][qt][v] * 0.125f;
          if (domask && (c * 64 + 16 * mt + 4 * g + v) > qg) s = -1e30f;
          st[mt][qt][v] = s;
          mx = fmaxf(mx, s);
        }
      mx = fmaxf(mx, __shfl_xor(mx, 16));
      mx = fmaxf(mx, __shfl_xor(mx, 32));
      const float mn = fmaxf(mrow[qt], mx);
      const float alpha = __expf(mrow[qt] - mn);
      mrow[qt] = mn;
      float psum = 0.f;
#pragma unroll
      for (int mt = 0; mt < 4; mt++) {
        unsigned short pk[4];
#pragma unroll
        for (int v = 0; v < 4; v++) {
          float p = __expf(st[mt][qt][v] - mn);
          psum += p;
          pk[v] = f2bf(p);
        }
        *(uint2*)&Pw[(16 * qt + l16) * 72 + 16 * mt + 4 * g] = *(const uint2*)pk;
      }
      psum += __shfl_xor(psum, 16);
      psum += __shfl_xor(psum, 32);
      lrow[qt] = lrow[qt] * alpha + psum;
      if (g == 0) als[w][16 * qt + l16] = alpha;
    }

    // rescale O accumulator (alpha indexed by row q = 4g+v within qt tile)
#pragma unroll
    for (int qt = 0; qt < 2; qt++) {
      float4 av = *(const float4*)&als[w][16 * qt + 4 * g];
#pragma unroll
      for (int dt = 0; dt < 4; dt++) {
        Oacc[qt][dt][0] *= av.x;
        Oacc[qt][dt][1] *= av.y;
        Oacc[qt][dt][2] *= av.z;
        Oacc[qt][dt][3] *= av.w;
      }
    }

    // PV: A = P (m=q, k=j), B = V^T (n=d, k=j)
#pragma unroll
    for (int ks = 0; ks < 2; ks++) {
      bf16x8 pf[2], vf[4];
#pragma unroll
      for (int qt = 0; qt < 2; qt++)
        pf[qt] = *(const bf16x8*)&Pw[(16 * qt + l16) * 72 + ks * 32 + g * 8];
#pragma unroll
      for (int dt = 0; dt < 4; dt++)
        vf[dt] = *(const bf16x8*)&Vs[(16 * dt + l16) * 72 + ks * 32 + g * 8];
#pragma unroll
      for (int qt = 0; qt < 2; qt++)
#pragma unroll
        for (int dt = 0; dt < 4; dt++)
          Oacc[qt][dt] = __builtin_amdgcn_mfma_f32_16x16x32_bf16(pf[qt], vf[dt], Oacc[qt][dt], 0, 0, 0);
    }
  }

  if (g == 0) { lls[w][l16] = lrow[0]; lls[w][16 + l16] = lrow[1]; }
  const int b = bh >> 4, h = bh & 15;
#pragma unroll
  for (int qt = 0; qt < 2; qt++) {
    float4 lv = *(const float4*)&lls[w][16 * qt + 4 * g];
    const float i0 = 1.f / lv.x, i1 = 1.f / lv.y, i2 = 1.f / lv.z, i3 = 1.f / lv.w;
#pragma unroll
    for (int dt = 0; dt < 4; dt++) {
      const int d = h * DHd + 16 * dt + l16;
      const size_t r0 = (size_t)(b * Tseq + q0w + 16 * qt + 4 * g) * Dmod + d;
      O[r0]            = f2bf(Oacc[qt][dt][0] * i0);
      O[r0 + Dmod]     = f2bf(Oacc[qt][dt][1] * i1);
      O[r0 + 2 * Dmod] = f2bf(Oacc[qt][dt][2] * i2);
      O[r0 + 3 * Dmod] = f2bf(Oacc[qt][dt][3] * i3);
    }
  }
}

extern "C" void kernel_launch(void* const* d_in, const int* in_sizes, int n_in,
                              void* d_out, int out_size, void* d_ws, size_t ws_size,
                              hipStream_t stream) {
  (void)in_sizes; (void)n_in; (void)out_size; (void)ws_size;
  const float* x     = (const float*)d_in[0];  // [B,T,D]   fp32
  const float* w_qkv = (const float*)d_in[1];  // [D,3D]    fp32
  const float* b_qkv = (const float*)d_in[2];  // [3D]      fp32
  const float* w_out = (const float*)d_in[3];  // [D,D]     fp32
  const float* b_out = (const float*)d_in[4];  // [D]       fp32
  float* out = (float*)d_out;                  // [B,T,D]   fp32

  unsigned short* ws    = (unsigned short*)d_ws;
  unsigned short* xb    = ws;                            // [B*T, D] bf16, reused as Ob
  unsigned short* wqkvT = xb    + (size_t)4194304;       // [3D][D]
  unsigned short* woutT = wqkvT + (size_t)3072 * 1024;   // [D][D]
  unsigned short* Qb    = woutT + (size_t)1024 * 1024;   // [B,H,T,DH]
  unsigned short* Kb    = Qb + (size_t)4194304;          // [B,H,T,DH]
  unsigned short* Vt    = Kb + (size_t)4194304;          // [B,H,DH,T] (transposed)
  unsigned short* Ob    = xb;  // reuse: xb dead after GEMM1

  cast_f32_bf16<<<2048, 256, 0, stream>>>(x, xb, 4194304);
  transpose_cast<<<dim3(48, 16), 256, 0, stream>>>(w_qkv, wqkvT, 1024, 3072);
  transpose_cast<<<dim3(16, 16), 256, 0, stream>>>(w_out, woutT, 1024, 1024);
  gemm_bt<<<dim3(32, 24), 256, 0, stream>>>(xb, wqkvT, b_qkv, 4096, 3072, 1024, 0,
                                            nullptr, Qb, Kb, Vt);
  attn_mfma<<<dim3(16, 32), 256, 0, stream>>>(Qb, Kb, Vt, Ob);
  gemm_bt<<<dim3(32, 8), 256, 0, stream>>>(Ob, woutT, b_out, 4096, 1024, 1024, 1,
                                           out, nullptr, nullptr, nullptr);
}

// Round 4
// 250.318 us; speedup vs baseline: 4.7341x; 1.0271x over previous
//
#include <hip/hip_runtime.h>
#include <hip/hip_bf16.h>
#include <stdint.h>

#define Bsz  2
#define Tseq 2048
#define Dmod 1024
#define Hn   16
#define DHd  64

typedef short bf16x8 __attribute__((ext_vector_type(8)));
typedef float f32x4 __attribute__((ext_vector_type(4)));

__device__ __forceinline__ float bf2f(unsigned short u) {
  union { unsigned int i; float f; } v; v.i = ((unsigned int)u) << 16; return v.f;
}
__device__ __forceinline__ unsigned short f2bf(float f) {
  union { float f; unsigned int i; } v; v.f = f;
  unsigned int r = (v.i + 0x7fffu + ((v.i >> 16) & 1u)) >> 16;
  return (unsigned short)r;
}
__device__ __forceinline__ unsigned int pk_bf16(float a, float b) {
  union { __hip_bfloat162 h; unsigned int u; } u2;
  u2.h = __float22bfloat162_rn(make_float2(a, b));
  return u2.u;
}
// async global->LDS, 16B per lane; LDS dest = wave-uniform base + lane*16
__device__ __forceinline__ void gl_lds16(const unsigned short* g, unsigned short* l) {
  __builtin_amdgcn_global_load_lds(
      (const __attribute__((address_space(1))) void*)g,
      (__attribute__((address_space(3))) void*)l, 16, 0, 0);
}

// ---------------- cast fp32 -> bf16, 8 elems/thread ----------------
__global__ __launch_bounds__(256) void cast_f32_bf16(const float* __restrict__ in,
                                                     unsigned short* __restrict__ out,
                                                     int n) {
  int idx = (blockIdx.x * 256 + threadIdx.x) * 8;
  if (idx + 8 > n) return;
  float4 a = *(const float4*)&in[idx];
  float4 b = *(const float4*)&in[idx + 4];
  unsigned short o[8];
  o[0] = f2bf(a.x); o[1] = f2bf(a.y); o[2] = f2bf(a.z); o[3] = f2bf(a.w);
  o[4] = f2bf(b.x); o[5] = f2bf(b.y); o[6] = f2bf(b.z); o[7] = f2bf(b.w);
  *(uint4*)&out[idx] = *(const uint4*)o;
}

// ---------------- transpose+cast: in fp32 [K][N] -> out bf16 [N][K] ----------------
__global__ __launch_bounds__(256) void transpose_cast(const float* __restrict__ in,
                                                      unsigned short* __restrict__ out,
                                                      int K, int N) {
  __shared__ unsigned short tile[64][65];
  const int k0 = blockIdx.y * 64, n0 = blockIdx.x * 64;
  for (int i = threadIdx.x; i < 4096; i += 256) {
    int r = i >> 6, c = i & 63;
    tile[r][c] = f2bf(in[(size_t)(k0 + r) * N + n0 + c]);
  }
  __syncthreads();
  for (int i = threadIdx.x; i < 4096; i += 256) {
    int r = i >> 6, c = i & 63;
    out[(size_t)(n0 + r) * K + k0 + c] = tile[c][r];
  }
}

// ---------------- GEMM: C[m][n] = sum_k A[m][k]*Bt[n][k] + bias[n] ----------------
// 128x128 tile, async global_load_lds staging (m97 pattern).
// mode 0: scatter bf16 to Q [B,H,T,DH] / K [B,H,T,DH] / V^T [B,H,DH,T]
// mode 1: write fp32 outF[m*N+n]
__global__ __launch_bounds__(256) void gemm_bt(const unsigned short* __restrict__ A,
                                               const unsigned short* __restrict__ Bt,
                                               const float* __restrict__ bias,
                                               int M, int N, int K, int mode,
                                               float* __restrict__ outF,
                                               unsigned short* __restrict__ out0,
                                               unsigned short* __restrict__ out1,
                                               unsigned short* __restrict__ out2) {
  __shared__ unsigned short As[128 * 64];
  __shared__ unsigned short Bs[128 * 64];
  const int tid  = threadIdx.x;
  const int lane = tid & 63;
  const int w    = tid >> 6;
  const int m0   = blockIdx.x * 128;
  const int n0   = blockIdx.y * 128;
  const int wr   = (w >> 1) * 64;
  const int wc   = (w & 1) * 64;

  f32x4 acc[4][4];
  for (int i = 0; i < 4; i++)
    for (int j = 0; j < 4; j++)
      for (int v = 0; v < 4; v++) acc[i][j][v] = 0.0f;

  const int l16 = lane & 15;
  const int q8  = (lane >> 4) * 8;

  // per-wave async staging pointers: wave w stages rows [32w, 32w+32) of As/Bs
  const unsigned short* ga[4];
  const unsigned short* gb[4];
  unsigned short* la[4];
  unsigned short* lb[4];
#pragma unroll
  for (int p = 0; p < 4; p++) {
    int r = 32 * w + 8 * p + (lane >> 3);
    ga[p] = A  + (size_t)(m0 + r) * K + (lane & 7) * 8;
    gb[p] = Bt + (size_t)(n0 + r) * K + (lane & 7) * 8;
    la[p] = &As[(32 * w + 8 * p) * 64];
    lb[p] = &Bs[(32 * w + 8 * p) * 64];
  }

  for (int kt = 0; kt < K; kt += 64) {
    __syncthreads();
#pragma unroll
    for (int p = 0; p < 4; p++) {
      gl_lds16(ga[p] + kt, la[p]);
      gl_lds16(gb[p] + kt, lb[p]);
    }
    __syncthreads();
#pragma unroll
    for (int ks = 0; ks < 2; ks++) {
      bf16x8 af[4], bf[4];
#pragma unroll
      for (int i = 0; i < 4; i++)
        af[i] = *(const bf16x8*)&As[(wr + i * 16 + l16) * 64 + ks * 32 + q8];
#pragma unroll
      for (int j = 0; j < 4; j++)
        bf[j] = *(const bf16x8*)&Bs[(wc + j * 16 + l16) * 64 + ks * 32 + q8];
#pragma unroll
      for (int i = 0; i < 4; i++)
#pragma unroll
        for (int j = 0; j < 4; j++)
          acc[i][j] = __builtin_amdgcn_mfma_f32_16x16x32_bf16(af[i], bf[j], acc[i][j], 0, 0, 0);
    }
  }

  const int q4 = (lane >> 4) * 4;
#pragma unroll
  for (int i = 0; i < 4; i++)
#pragma unroll
    for (int j = 0; j < 4; j++) {
      const int mbase = m0 + wr + i * 16 + q4;
      const int n = n0 + wc + j * 16 + l16;
      float vals[4];
#pragma unroll
      for (int v = 0; v < 4; v++) vals[v] = acc[i][j][v] + bias[n];
      if (mode == 1) {
#pragma unroll
        for (int v = 0; v < 4; v++)
          outF[(size_t)(mbase + v) * N + n] = vals[v];
      } else {
        const int which = n >> 10;
        const int rem = n & 1023;
        const int h = rem >> 6, dd = rem & 63;
        const int b = mbase >> 11, t = mbase & 2047;  // t..t+3 within same b
        if (which == 2) {
          uint2 uu;
          uu.x = pk_bf16(vals[0], vals[1]);
          uu.y = pk_bf16(vals[2], vals[3]);
          *(uint2*)&out2[((size_t)((b * Hn + h) * DHd + dd)) * Tseq + t] = uu;
        } else {
          unsigned short* dst = (which == 0) ? out0 : out1;
#pragma unroll
          for (int v = 0; v < 4; v++)
            dst[(size_t)((b * Hn + h) * Tseq + t + v) * DHd + dd] = f2bf(vals[v]);
        }
      }
    }
}

// ---------------- MFMA causal flash attention ----------------
// grid (32, B*H) heavy-first; block 256 = 4 waves; wave w owns 16 q-rows.
// S^T = MFMA(A=K, B=Q): col=q (lane&15), row=j ((lane>>4)*4+v). exp2-domain softmax.
// P^T -> LDS [q][j], PV = MFMA(A=P, B=V^T)
__global__ __launch_bounds__(256, 4) void attn_mfma(const unsigned short* __restrict__ Qb,
                                                    const unsigned short* __restrict__ Kb,
                                                    const unsigned short* __restrict__ Vtg,
                                                    unsigned short* __restrict__ O) {
  __shared__ unsigned short Ks[64 * 72];      // [j][d]
  __shared__ unsigned short Vs[64 * 72];      // [d][j]
  __shared__ unsigned short Ps[4 * 16 * 72];  // per-wave [q][j]
  __shared__ float als[4][16];
  __shared__ float lls[4][16];

  const int tid  = threadIdx.x;
  const int lane = tid & 63;
  const int w    = tid >> 6;
  const int g    = lane >> 4;
  const int l16  = lane & 15;
  const int tile = gridDim.x - 1 - blockIdx.x;   // heavy blocks first
  const int bh   = blockIdx.y;
  const int q0w  = tile * 64 + w * 16;

  const unsigned short* Qp = Qb  + (size_t)bh * Tseq * DHd;
  const unsigned short* Kp = Kb  + (size_t)bh * Tseq * DHd;
  const unsigned short* Vp = Vtg + (size_t)bh * DHd * Tseq;

  // Q B-fragments from global: n=q (l16), k=d (g*8..)
  bf16x8 qf[2];
#pragma unroll
  for (int ks = 0; ks < 2; ks++)
    qf[ks] = *(const bf16x8*)&Qp[(size_t)(q0w + l16) * DHd + ks * 32 + g * 8];

  f32x4 Oacc[4];
#pragma unroll
  for (int dt = 0; dt < 4; dt++)
#pragma unroll
    for (int v = 0; v < 4; v++) Oacc[dt][v] = 0.f;

  float mrow = -1e30f, lrow = 0.f;
  unsigned short* Pw = &Ps[w * 16 * 72];
  const int srow = tid >> 3;        // 0..31
  const int sg8  = (tid & 7) * 8;

  for (int c = 0; c <= tile; c++) {
    __syncthreads();
#pragma unroll
    for (int i = 0; i < 2; i++) {
      int row = srow + 32 * i;
      *(uint4*)&Ks[row * 72 + sg8] = *(const uint4*)&Kp[(size_t)(c * 64 + row) * DHd + sg8];
      *(uint4*)&Vs[row * 72 + sg8] = *(const uint4*)&Vp[(size_t)row * Tseq + c * 64 + sg8];
    }
    __syncthreads();

    // S^T tiles over j
    f32x4 st[4];
#pragma unroll
    for (int mt = 0; mt < 4; mt++)
#pragma unroll
      for (int v = 0; v < 4; v++) st[mt][v] = 0.f;
#pragma unroll
    for (int ks = 0; ks < 2; ks++) {
      bf16x8 kf[4];
#pragma unroll
      for (int mt = 0; mt < 4; mt++)
        kf[mt] = *(const bf16x8*)&Ks[(16 * mt + l16) * 72 + ks * 32 + g * 8];
#pragma unroll
      for (int mt = 0; mt < 4; mt++)
        st[mt] = __builtin_amdgcn_mfma_f32_16x16x32_bf16(kf[mt], qf[ks], st[mt], 0, 0, 0);
    }

    const float SC = 0.1803368801f;  // 0.125 * log2(e)
    const bool dm = (c == tile);
    const int qg = q0w + l16;
    float mx = -1e30f;
#pragma unroll
    for (int mt = 0; mt < 4; mt++)
#pragma unroll
      for (int v = 0; v < 4; v++) {
        float s = st[mt][v] * SC;
        if (dm && (c * 64 + 16 * mt + 4 * g + v) > qg) s = -1e30f;
        st[mt][v] = s;
        mx = fmaxf(mx, s);
      }
    mx = fmaxf(mx, __shfl_xor(mx, 16));
    mx = fmaxf(mx, __shfl_xor(mx, 32));
    const float mn = fmaxf(mrow, mx);
    const float alpha = __builtin_exp2f(mrow - mn);
    mrow = mn;
    float psum = 0.f;
#pragma unroll
    for (int mt = 0; mt < 4; mt++) {
      float p[4];
#pragma unroll
      for (int v = 0; v < 4; v++) { p[v] = __builtin_exp2f(st[mt][v] - mn); psum += p[v]; }
      uint2 uu;
      uu.x = pk_bf16(p[0], p[1]);
      uu.y = pk_bf16(p[2], p[3]);
      *(uint2*)&Pw[l16 * 72 + 16 * mt + 4 * g] = uu;
    }
    psum += __shfl_xor(psum, 16);
    psum += __shfl_xor(psum, 32);
    lrow = lrow * alpha + psum;
    if (g == 0) als[w][l16] = alpha;

    // rescale O (rows q = 4g+v)
    float4 av = *(const float4*)&als[w][4 * g];
#pragma unroll
    for (int dt = 0; dt < 4; dt++) {
      Oacc[dt][0] *= av.x;
      Oacc[dt][1] *= av.y;
      Oacc[dt][2] *= av.z;
      Oacc[dt][3] *= av.w;
    }

    // PV: A = P (m=q, k=j), B = V^T (n=d, k=j)
#pragma unroll
    for (int ks = 0; ks < 2; ks++) {
      bf16x8 pf = *(const bf16x8*)&Pw[l16 * 72 + ks * 32 + g * 8];
      bf16x8 vf[4];
#pragma unroll
      for (int dt = 0; dt < 4; dt++)
        vf[dt] = *(const bf16x8*)&Vs[(16 * dt + l16) * 72 + ks * 32 + g * 8];
#pragma unroll
      for (int dt = 0; dt < 4; dt++)
        Oacc[dt] = __builtin_amdgcn_mfma_f32_16x16x32_bf16(pf, vf[dt], Oacc[dt], 0, 0, 0);
    }
  }

  if (g == 0) lls[w][l16] = lrow;
  float4 lv = *(const float4*)&lls[w][4 * g];
  const float i0 = 1.f / lv.x, i1 = 1.f / lv.y, i2 = 1.f / lv.z, i3 = 1.f / lv.w;
  const int b = bh >> 4, h = bh & 15;
#pragma unroll
  for (int dt = 0; dt < 4; dt++) {
    const int d = h * DHd + 16 * dt + l16;
    const size_t r0 = (size_t)(b * Tseq + q0w + 4 * g) * Dmod + d;
    O[r0]            = f2bf(Oacc[dt][0] * i0);
    O[r0 + Dmod]     = f2bf(Oacc[dt][1] * i1);
    O[r0 + 2 * Dmod] = f2bf(Oacc[dt][2] * i2);
    O[r0 + 3 * Dmod] = f2bf(Oacc[dt][3] * i3);
  }
}

extern "C" void kernel_launch(void* const* d_in, const int* in_sizes, int n_in,
                              void* d_out, int out_size, void* d_ws, size_t ws_size,
                              hipStream_t stream) {
  (void)in_sizes; (void)n_in; (void)out_size; (void)ws_size;
  const float* x     = (const float*)d_in[0];  // [B,T,D]   fp32
  const float* w_qkv = (const float*)d_in[1];  // [D,3D]    fp32
  const float* b_qkv = (const float*)d_in[2];  // [3D]      fp32
  const float* w_out = (const float*)d_in[3];  // [D,D]     fp32
  const float* b_out = (const float*)d_in[4];  // [D]       fp32
  float* out = (float*)d_out;                  // [B,T,D]   fp32

  unsigned short* ws    = (unsigned short*)d_ws;
  unsigned short* xb    = ws;                            // [B*T, D] bf16, reused as Ob
  unsigned short* wqkvT = xb    + (size_t)4194304;       // [3D][D]
  unsigned short* woutT = wqkvT + (size_t)3072 * 1024;   // [D][D]
  unsigned short* Qb    = woutT + (size_t)1024 * 1024;   // [B,H,T,DH]
  unsigned short* Kb    = Qb + (size_t)4194304;          // [B,H,T,DH]
  unsigned short* Vt    = Kb + (size_t)4194304;          // [B,H,DH,T] (transposed)
  unsigned short* Ob    = xb;  // reuse: xb dead after GEMM1

  cast_f32_bf16<<<2048, 256, 0, stream>>>(x, xb, 4194304);
  transpose_cast<<<dim3(48, 16), 256, 0, stream>>>(w_qkv, wqkvT, 1024, 3072);
  transpose_cast<<<dim3(16, 16), 256, 0, stream>>>(w_out, woutT, 1024, 1024);
  gemm_bt<<<dim3(32, 24), 256, 0, stream>>>(xb, wqkvT, b_qkv, 4096, 3072, 1024, 0,
                                            nullptr, Qb, Kb, Vt);
  attn_mfma<<<dim3(32, 32), 256, 0, stream>>>(Qb, Kb, Vt, Ob);
  gemm_bt<<<dim3(32, 8), 256, 0, stream>>>(Ob, woutT, b_out, 4096, 1024, 1024, 1,
                                           out, nullptr, nullptr, nullptr);
}

// Round 5
// 212.788 us; speedup vs baseline: 5.5690x; 1.1764x over previous
//
#include <hip/hip_runtime.h>
#include <hip/hip_bf16.h>
#include <stdint.h>

#define Bsz  2
#define Tseq 2048
#define Dmod 1024
#define Hn   16
#define DHd  64

typedef short bf16x8 __attribute__((ext_vector_type(8)));
typedef float f32x4 __attribute__((ext_vector_type(4)));

__device__ __forceinline__ float bf2f(unsigned short u) {
  union { unsigned int i; float f; } v; v.i = ((unsigned int)u) << 16; return v.f;
}
__device__ __forceinline__ unsigned short f2bf(float f) {
  union { float f; unsigned int i; } v; v.f = f;
  unsigned int r = (v.i + 0x7fffu + ((v.i >> 16) & 1u)) >> 16;
  return (unsigned short)r;
}
__device__ __forceinline__ unsigned int pk_bf16(float a, float b) {
  union { __hip_bfloat162 h; unsigned int u; } u2;
  u2.h = __float22bfloat162_rn(make_float2(a, b));
  return u2.u;
}
// async global->LDS, 16B per lane; LDS dest = wave-uniform base + lane*16
__device__ __forceinline__ void gl_lds16(const unsigned short* g, unsigned short* l) {
  __builtin_amdgcn_global_load_lds(
      (const __attribute__((address_space(1))) void*)g,
      (__attribute__((address_space(3))) void*)l, 16, 0, 0);
}

// ---------------- cast fp32 -> bf16, 8 elems/thread ----------------
__global__ __launch_bounds__(256) void cast_f32_bf16(const float* __restrict__ in,
                                                     unsigned short* __restrict__ out,
                                                     int n) {
  int idx = (blockIdx.x * 256 + threadIdx.x) * 8;
  if (idx + 8 > n) return;
  float4 a = *(const float4*)&in[idx];
  float4 b = *(const float4*)&in[idx + 4];
  unsigned short o[8];
  o[0] = f2bf(a.x); o[1] = f2bf(a.y); o[2] = f2bf(a.z); o[3] = f2bf(a.w);
  o[4] = f2bf(b.x); o[5] = f2bf(b.y); o[6] = f2bf(b.z); o[7] = f2bf(b.w);
  *(uint4*)&out[idx] = *(const uint4*)o;
}

// ---------------- transpose+cast: in fp32 [K][N] -> out bf16 [N][K] ----------------
__global__ __launch_bounds__(256) void transpose_cast(const float* __restrict__ in,
                                                      unsigned short* __restrict__ out,
                                                      int K, int N) {
  __shared__ unsigned short tile[64][65];
  const int k0 = blockIdx.y * 64, n0 = blockIdx.x * 64;
  for (int i = threadIdx.x; i < 4096; i += 256) {
    int r = i >> 6, c = i & 63;
    tile[r][c] = f2bf(in[(size_t)(k0 + r) * N + n0 + c]);
  }
  __syncthreads();
  for (int i = threadIdx.x; i < 4096; i += 256) {
    int r = i >> 6, c = i & 63;
    out[(size_t)(n0 + r) * K + k0 + c] = tile[c][r];
  }
}

// ---------------- GEMM: C[m][n] = sum_k A[m][k]*Bt[n][k] + bias[n] ----------------
// 128x128 tile, async global_load_lds staging (m97 pattern).
// mode 0: scatter bf16 to Q [B,H,T,DH] / K [B,H,T,DH] / V^T [B,H,DH,T]
// mode 1: write fp32 outF[m*N+n]
__global__ __launch_bounds__(256) void gemm_bt(const unsigned short* __restrict__ A,
                                               const unsigned short* __restrict__ Bt,
                                               const float* __restrict__ bias,
                                               int M, int N, int K, int mode,
                                               float* __restrict__ outF,
                                               unsigned short* __restrict__ out0,
                                               unsigned short* __restrict__ out1,
                                               unsigned short* __restrict__ out2) {
  __shared__ unsigned short As[128 * 64];
  __shared__ unsigned short Bs[128 * 64];
  const int tid  = threadIdx.x;
  const int lane = tid & 63;
  const int w    = tid >> 6;
  const int m0   = blockIdx.x * 128;
  const int n0   = blockIdx.y * 128;
  const int wr   = (w >> 1) * 64;
  const int wc   = (w & 1) * 64;

  f32x4 acc[4][4];
  for (int i = 0; i < 4; i++)
    for (int j = 0; j < 4; j++)
      for (int v = 0; v < 4; v++) acc[i][j][v] = 0.0f;

  const int l16 = lane & 15;
  const int q8  = (lane >> 4) * 8;

  const unsigned short* ga[4];
  const unsigned short* gb[4];
  unsigned short* la[4];
  unsigned short* lb[4];
#pragma unroll
  for (int p = 0; p < 4; p++) {
    int r = 32 * w + 8 * p + (lane >> 3);
    ga[p] = A  + (size_t)(m0 + r) * K + (lane & 7) * 8;
    gb[p] = Bt + (size_t)(n0 + r) * K + (lane & 7) * 8;
    la[p] = &As[(32 * w + 8 * p) * 64];
    lb[p] = &Bs[(32 * w + 8 * p) * 64];
  }

  for (int kt = 0; kt < K; kt += 64) {
    __syncthreads();
#pragma unroll
    for (int p = 0; p < 4; p++) {
      gl_lds16(ga[p] + kt, la[p]);
      gl_lds16(gb[p] + kt, lb[p]);
    }
    __syncthreads();
#pragma unroll
    for (int ks = 0; ks < 2; ks++) {
      bf16x8 af[4], bf[4];
#pragma unroll
      for (int i = 0; i < 4; i++)
        af[i] = *(const bf16x8*)&As[(wr + i * 16 + l16) * 64 + ks * 32 + q8];
#pragma unroll
      for (int j = 0; j < 4; j++)
        bf[j] = *(const bf16x8*)&Bs[(wc + j * 16 + l16) * 64 + ks * 32 + q8];
#pragma unroll
      for (int i = 0; i < 4; i++)
#pragma unroll
        for (int j = 0; j < 4; j++)
          acc[i][j] = __builtin_amdgcn_mfma_f32_16x16x32_bf16(af[i], bf[j], acc[i][j], 0, 0, 0);
    }
  }

  const int q4 = (lane >> 4) * 4;
#pragma unroll
  for (int i = 0; i < 4; i++)
#pragma unroll
    for (int j = 0; j < 4; j++) {
      const int mbase = m0 + wr + i * 16 + q4;
      const int n = n0 + wc + j * 16 + l16;
      float vals[4];
#pragma unroll
      for (int v = 0; v < 4; v++) vals[v] = acc[i][j][v] + bias[n];
      if (mode == 1) {
#pragma unroll
        for (int v = 0; v < 4; v++)
          outF[(size_t)(mbase + v) * N + n] = vals[v];
      } else {
        const int which = n >> 10;
        const int rem = n & 1023;
        const int h = rem >> 6, dd = rem & 63;
        const int b = mbase >> 11, t = mbase & 2047;  // t..t+3 within same b
        if (which == 2) {
          uint2 uu;
          uu.x = pk_bf16(vals[0], vals[1]);
          uu.y = pk_bf16(vals[2], vals[3]);
          *(uint2*)&out2[((size_t)((b * Hn + h) * DHd + dd)) * Tseq + t] = uu;
        } else {
          unsigned short* dst = (which == 0) ? out0 : out1;
#pragma unroll
          for (int v = 0; v < 4; v++)
            dst[(size_t)((b * Hn + h) * Tseq + t + v) * DHd + dd] = f2bf(vals[v]);
        }
      }
    }
}

// ---------------- MFMA causal flash attention, double-buffered K/V ----------------
// grid (bh=32, tiles=32 heavy-first); block 256 = 4 waves; wave w owns 16 q-rows.
// Per chunk: prefetch c+1 globals -> regs, compute c from LDS buf c&1,
// ds_write prefetch -> buf (c+1)&1, ONE __syncthreads.
// S^T = MFMA(A=K, B=Q): col=q (l16), row=j (4g+v). exp2-domain softmax.
__global__ __launch_bounds__(256, 3) void attn_mfma(const unsigned short* __restrict__ Qb,
                                                    const unsigned short* __restrict__ Kb,
                                                    const unsigned short* __restrict__ Vtg,
                                                    unsigned short* __restrict__ O) {
  __shared__ unsigned short Ks[2][64 * 72];   // [j][d]
  __shared__ unsigned short Vs[2][64 * 72];   // [d][j]
  __shared__ unsigned short Ps[4][16 * 72];   // per-wave [q][j]

  const int tid  = threadIdx.x;
  const int lane = tid & 63;
  const int w    = tid >> 6;
  const int g    = lane >> 4;
  const int l16  = lane & 15;
  const int bh   = blockIdx.x;
  const int tile = (int)gridDim.y - 1 - (int)blockIdx.y;   // heavy blocks first
  const int q0w  = tile * 64 + w * 16;

  const unsigned short* Qp = Qb  + (size_t)bh * Tseq * DHd;
  const unsigned short* Kp = Kb  + (size_t)bh * Tseq * DHd;
  const unsigned short* Vp = Vtg + (size_t)bh * DHd * Tseq;

  // Q B-fragments from global: n=q (l16), k=d (g*8..)
  bf16x8 qf[2];
#pragma unroll
  for (int ks = 0; ks < 2; ks++)
    qf[ks] = *(const bf16x8*)&Qp[(size_t)(q0w + l16) * DHd + ks * 32 + g * 8];

  f32x4 Oacc[4];
#pragma unroll
  for (int dt = 0; dt < 4; dt++)
#pragma unroll
    for (int v = 0; v < 4; v++) Oacc[dt][v] = 0.f;

  float mrow = -1e30f, lrow = 0.f;
  unsigned short* Pw = Ps[w];
  const int srow = tid >> 3;        // 0..31
  const int sg8  = (tid & 7) * 8;

  const unsigned short* Kg0 = Kp + (size_t)srow * DHd + sg8;
  const unsigned short* Kg1 = Kp + (size_t)(srow + 32) * DHd + sg8;
  const unsigned short* Vg0 = Vp + (size_t)srow * Tseq + sg8;
  const unsigned short* Vg1 = Vp + (size_t)(srow + 32) * Tseq + sg8;

  // stage chunk 0 -> buf 0
  {
    uint4 k0 = *(const uint4*)Kg0;
    uint4 k1 = *(const uint4*)Kg1;
    uint4 v0 = *(const uint4*)Vg0;
    uint4 v1 = *(const uint4*)Vg1;
    *(uint4*)&Ks[0][srow * 72 + sg8]        = k0;
    *(uint4*)&Ks[0][(srow + 32) * 72 + sg8] = k1;
    *(uint4*)&Vs[0][srow * 72 + sg8]        = v0;
    *(uint4*)&Vs[0][(srow + 32) * 72 + sg8] = v1;
  }
  __syncthreads();

  for (int c = 0; c <= tile; c++) {
    const int cur = c & 1, nxt = cur ^ 1;
    const bool pref = (c < tile);
    uint4 pk0, pk1, pv0, pv1;
    if (pref) {
      const size_t ko = (size_t)(c + 1) * 64 * DHd;
      const int    vo = (c + 1) * 64;
      pk0 = *(const uint4*)(Kg0 + ko);
      pk1 = *(const uint4*)(Kg1 + ko);
      pv0 = *(const uint4*)(Vg0 + vo);
      pv1 = *(const uint4*)(Vg1 + vo);
    }

    // S^T tiles over j
    f32x4 st[4];
#pragma unroll
    for (int mt = 0; mt < 4; mt++)
#pragma unroll
      for (int v = 0; v < 4; v++) st[mt][v] = 0.f;
#pragma unroll
    for (int ks = 0; ks < 2; ks++) {
      bf16x8 kf[4];
#pragma unroll
      for (int mt = 0; mt < 4; mt++)
        kf[mt] = *(const bf16x8*)&Ks[cur][(16 * mt + l16) * 72 + ks * 32 + g * 8];
#pragma unroll
      for (int mt = 0; mt < 4; mt++)
        st[mt] = __builtin_amdgcn_mfma_f32_16x16x32_bf16(kf[mt], qf[ks], st[mt], 0, 0, 0);
    }

    const float SC = 0.1803368801f;  // 0.125 * log2(e)
    float mx = -1e30f;
    if (c == tile) {  // wave-uniform: only diagonal chunk pays masking
      const int qg = q0w + l16;
#pragma unroll
      for (int mt = 0; mt < 4; mt++)
#pragma unroll
        for (int v = 0; v < 4; v++) {
          float s = st[mt][v] * SC;
          if ((c * 64 + 16 * mt + 4 * g + v) > qg) s = -1e30f;
          st[mt][v] = s;
          mx = fmaxf(mx, s);
        }
    } else {
#pragma unroll
      for (int mt = 0; mt < 4; mt++)
#pragma unroll
        for (int v = 0; v < 4; v++) {
          float s = st[mt][v] * SC;
          st[mt][v] = s;
          mx = fmaxf(mx, s);
        }
    }
    mx = fmaxf(mx, __shfl_xor(mx, 16));
    mx = fmaxf(mx, __shfl_xor(mx, 32));
    const float mn = fmaxf(mrow, mx);
    const float alpha = __builtin_exp2f(mrow - mn);
    mrow = mn;
    float psum = 0.f;
#pragma unroll
    for (int mt = 0; mt < 4; mt++) {
      float p[4];
#pragma unroll
      for (int v = 0; v < 4; v++) { p[v] = __builtin_exp2f(st[mt][v] - mn); psum += p[v]; }
      uint2 uu;
      uu.x = pk_bf16(p[0], p[1]);
      uu.y = pk_bf16(p[2], p[3]);
      *(uint2*)&Pw[l16 * 72 + 16 * mt + 4 * g] = uu;
    }
    psum += __shfl_xor(psum, 16);
    psum += __shfl_xor(psum, 32);
    lrow = lrow * alpha + psum;

    // broadcast alpha to rows q = 4g+v via shuffle (lane 4g+v holds that row's alpha)
    const float a0 = __shfl(alpha, 4 * g + 0);
    const float a1 = __shfl(alpha, 4 * g + 1);
    const float a2 = __shfl(alpha, 4 * g + 2);
    const float a3 = __shfl(alpha, 4 * g + 3);
#pragma unroll
    for (int dt = 0; dt < 4; dt++) {
      Oacc[dt][0] *= a0;
      Oacc[dt][1] *= a1;
      Oacc[dt][2] *= a2;
      Oacc[dt][3] *= a3;
    }

    // PV: A = P (m=q, k=j), B = V^T (n=d, k=j)
#pragma unroll
    for (int ks = 0; ks < 2; ks++) {
      bf16x8 pf = *(const bf16x8*)&Pw[l16 * 72 + ks * 32 + g * 8];
      bf16x8 vf[4];
#pragma unroll
      for (int dt = 0; dt < 4; dt++)
        vf[dt] = *(const bf16x8*)&Vs[cur][(16 * dt + l16) * 72 + ks * 32 + g * 8];
#pragma unroll
      for (int dt = 0; dt < 4; dt++)
        Oacc[dt] = __builtin_amdgcn_mfma_f32_16x16x32_bf16(pf, vf[dt], Oacc[dt], 0, 0, 0);
    }

    if (pref) {
      *(uint4*)&Ks[nxt][srow * 72 + sg8]        = pk0;
      *(uint4*)&Ks[nxt][(srow + 32) * 72 + sg8] = pk1;
      *(uint4*)&Vs[nxt][srow * 72 + sg8]        = pv0;
      *(uint4*)&Vs[nxt][(srow + 32) * 72 + sg8] = pv1;
      __syncthreads();
    }
  }

  const float l0 = __shfl(lrow, 4 * g + 0);
  const float l1 = __shfl(lrow, 4 * g + 1);
  const float l2 = __shfl(lrow, 4 * g + 2);
  const float l3 = __shfl(lrow, 4 * g + 3);
  const float i0 = 1.f / l0, i1 = 1.f / l1, i2 = 1.f / l2, i3 = 1.f / l3;
  const int b = bh >> 4, h = bh & 15;
#pragma unroll
  for (int dt = 0; dt < 4; dt++) {
    const int d = h * DHd + 16 * dt + l16;
    const size_t r0 = (size_t)(b * Tseq + q0w + 4 * g) * Dmod + d;
    O[r0]            = f2bf(Oacc[dt][0] * i0);
    O[r0 + Dmod]     = f2bf(Oacc[dt][1] * i1);
    O[r0 + 2 * Dmod] = f2bf(Oacc[dt][2] * i2);
    O[r0 + 3 * Dmod] = f2bf(Oacc[dt][3] * i3);
  }
}

extern "C" void kernel_launch(void* const* d_in, const int* in_sizes, int n_in,
                              void* d_out, int out_size, void* d_ws, size_t ws_size,
                              hipStream_t stream) {
  (void)in_sizes; (void)n_in; (void)out_size; (void)ws_size;
  const float* x     = (const float*)d_in[0];  // [B,T,D]   fp32
  const float* w_qkv = (const float*)d_in[1];  // [D,3D]    fp32
  const float* b_qkv = (const float*)d_in[2];  // [3D]      fp32
  const float* w_out = (const float*)d_in[3];  // [D,D]     fp32
  const float* b_out = (const float*)d_in[4];  // [D]       fp32
  float* out = (float*)d_out;                  // [B,T,D]   fp32

  unsigned short* ws    = (unsigned short*)d_ws;
  unsigned short* xb    = ws;                            // [B*T, D] bf16, reused as Ob
  unsigned short* wqkvT = xb    + (size_t)4194304;       // [3D][D]
  unsigned short* woutT = wqkvT + (size_t)3072 * 1024;   // [D][D]
  unsigned short* Qb    = woutT + (size_t)1024 * 1024;   // [B,H,T,DH]
  unsigned short* Kb    = Qb + (size_t)4194304;          // [B,H,T,DH]
  unsigned short* Vt    = Kb + (size_t)4194304;          // [B,H,DH,T] (transposed)
  unsigned short* Ob    = xb;  // reuse: xb dead after GEMM1

  cast_f32_bf16<<<2048, 256, 0, stream>>>(x, xb, 4194304);
  transpose_cast<<<dim3(48, 16), 256, 0, stream>>>(w_qkv, wqkvT, 1024, 3072);
  transpose_cast<<<dim3(16, 16), 256, 0, stream>>>(w_out, woutT, 1024, 1024);
  gemm_bt<<<dim3(32, 24), 256, 0, stream>>>(xb, wqkvT, b_qkv, 4096, 3072, 1024, 0,
                                            nullptr, Qb, Kb, Vt);
  attn_mfma<<<dim3(32, 32), 256, 0, stream>>>(Qb, Kb, Vt, Ob);
  gemm_bt<<<dim3(32, 8), 256, 0, stream>>>(Ob, woutT, b_out, 4096, 1024, 1024, 1,
                                           out, nullptr, nullptr, nullptr);
}

// Round 6
// 179.473 us; speedup vs baseline: 6.6028x; 1.1856x over previous
//
#include <hip/hip_runtime.h>
#include <hip/hip_bf16.h>
#include <stdint.h>

#define Bsz  2
#define Tseq 2048
#define Dmod 1024
#define Hn   16
#define DHd  64

typedef short bf16x8 __attribute__((ext_vector_type(8)));
typedef float f32x4 __attribute__((ext_vector_type(4)));

__device__ __forceinline__ float bf2f(unsigned short u) {
  union { unsigned int i; float f; } v; v.i = ((unsigned int)u) << 16; return v.f;
}
__device__ __forceinline__ unsigned short f2bf(float f) {
  union { float f; unsigned int i; } v; v.f = f;
  unsigned int r = (v.i + 0x7fffu + ((v.i >> 16) & 1u)) >> 16;
  return (unsigned short)r;
}
__device__ __forceinline__ unsigned int pk_bf16(float a, float b) {
  union { __hip_bfloat162 h; unsigned int u; } u2;
  u2.h = __float22bfloat162_rn(make_float2(a, b));
  return u2.u;
}
// async global->LDS, 16B per lane; LDS dest = wave-uniform base + lane*16
__device__ __forceinline__ void gl_lds16(const unsigned short* g, unsigned short* l) {
  __builtin_amdgcn_global_load_lds(
      (const __attribute__((address_space(1))) void*)g,
      (__attribute__((address_space(3))) void*)l, 16, 0, 0);
}

// ---------------- fused prep: cast x -> bf16, transpose+cast w_qkv & w_out ----------------
// blocks [0,2048): cast 2048 elems each; [2048,2816): w_qkv tiles (48x16); [2816,3072): w_out (16x16)
__global__ __launch_bounds__(256) void prep(const float* __restrict__ x,
                                            const float* __restrict__ w_qkv,
                                            const float* __restrict__ w_out,
                                            unsigned short* __restrict__ xb,
                                            unsigned short* __restrict__ wqkvT,
                                            unsigned short* __restrict__ woutT) {
  __shared__ unsigned short tile[64][65];
  const int blk = blockIdx.x;
  if (blk < 2048) {
    int idx = blk * 2048 + threadIdx.x * 8;
    float4 a = *(const float4*)&x[idx];
    float4 b = *(const float4*)&x[idx + 4];
    unsigned short o[8];
    o[0] = f2bf(a.x); o[1] = f2bf(a.y); o[2] = f2bf(a.z); o[3] = f2bf(a.w);
    o[4] = f2bf(b.x); o[5] = f2bf(b.y); o[6] = f2bf(b.z); o[7] = f2bf(b.w);
    *(uint4*)&xb[idx] = *(const uint4*)o;
    return;
  }
  const float* in;
  unsigned short* out;
  int K = 1024, N, k0, n0;
  if (blk < 2048 + 768) {
    int t = blk - 2048;
    in = w_qkv; out = wqkvT; N = 3072;
    n0 = (t % 48) * 64; k0 = (t / 48) * 64;
  } else {
    int t = blk - 2816;
    in = w_out; out = woutT; N = 1024;
    n0 = (t % 16) * 64; k0 = (t / 16) * 64;
  }
  for (int i = threadIdx.x; i < 4096; i += 256) {
    int r = i >> 6, c = i & 63;
    tile[r][c] = f2bf(in[(size_t)(k0 + r) * N + n0 + c]);
  }
  __syncthreads();
  for (int i = threadIdx.x; i < 4096; i += 256) {
    int r = i >> 6, c = i & 63;
    out[(size_t)(n0 + r) * K + k0 + c] = tile[c][r];
  }
}

// ---------------- GEMM: C[m][n] = sum_k A[m][k]*Bt[n][k] + bias[n] ----------------
// Tile 128 x NT, BK=64, async global_load_lds staging, XOR-swizzled LDS:
// physical 16B-block cp = logical cb ^ (row & 7)  -> conflict-free ds_read_b128.
// mode 0 (NT=128): scatter bf16 to Q [B,H,T,DH] / K [B,H,T,DH] / V^T [B,H,DH,T]
// mode 1: write fp32 outF[m*N+n]
template<int NT>
__global__ __launch_bounds__(256) void gemm_bt(const unsigned short* __restrict__ A,
                                               const unsigned short* __restrict__ Bt,
                                               const float* __restrict__ bias,
                                               int M, int N, int K, int mode,
                                               float* __restrict__ outF,
                                               unsigned short* __restrict__ out0,
                                               unsigned short* __restrict__ out1,
                                               unsigned short* __restrict__ out2) {
  constexpr int JT = NT / 32;   // j-tiles per wave
  constexpr int BP = NT / 32;   // B staging iterations
  __shared__ unsigned short As[128 * 64];
  __shared__ unsigned short Bs[NT * 64];
  const int tid  = threadIdx.x;
  const int lane = tid & 63;
  const int w    = tid >> 6;
  const int m0   = blockIdx.x * 128;
  const int n0   = blockIdx.y * NT;
  const int wr   = (w >> 1) * 64;
  const int wc   = (w & 1) * (NT / 2);

  f32x4 acc[4][JT];
  for (int i = 0; i < 4; i++)
    for (int j = 0; j < JT; j++)
      for (int v = 0; v < 4; v++) acc[i][j][v] = 0.0f;

  const int l16 = lane & 63 & 15;
  const int g   = lane >> 4;
  const int sw  = l16 & 7;      // fragment-read swizzle key

  // staging: lane -> physical slot (row8 = lane>>3, cp = lane&7); global col = (cp ^ row8)*8
  const int csw = (((lane & 7) ^ (lane >> 3)) & 7) * 8;
  const unsigned short* ga[4];
  const unsigned short* gb[BP];
  unsigned short* la[4];
  unsigned short* lb[BP];
#pragma unroll
  for (int p = 0; p < 4; p++) {
    int r = 32 * w + 8 * p + (lane >> 3);
    ga[p] = A + (size_t)(m0 + r) * K + csw;
    la[p] = &As[(32 * w + 8 * p) * 64];
  }
#pragma unroll
  for (int p = 0; p < BP; p++) {
    int r = (NT / 4) * w + 8 * p + (lane >> 3);
    gb[p] = Bt + (size_t)(n0 + r) * K + csw;
    lb[p] = &Bs[((NT / 4) * w + 8 * p) * 64];
  }

  for (int kt = 0; kt < K; kt += 64) {
    __syncthreads();
#pragma unroll
    for (int p = 0; p < 4; p++) gl_lds16(ga[p] + kt, la[p]);
#pragma unroll
    for (int p = 0; p < BP; p++) gl_lds16(gb[p] + kt, lb[p]);
    __syncthreads();
#pragma unroll
    for (int ks = 0; ks < 2; ks++) {
      bf16x8 af[4], bf[JT];
#pragma unroll
      for (int i = 0; i < 4; i++)
        af[i] = *(const bf16x8*)&As[(wr + i * 16 + l16) * 64 + (((ks * 4 + g) ^ sw) * 8)];
#pragma unroll
      for (int j = 0; j < JT; j++)
        bf[j] = *(const bf16x8*)&Bs[(wc + j * 16 + l16) * 64 + (((ks * 4 + g) ^ sw) * 8)];
#pragma unroll
      for (int i = 0; i < 4; i++)
#pragma unroll
        for (int j = 0; j < JT; j++)
          acc[i][j] = __builtin_amdgcn_mfma_f32_16x16x32_bf16(af[i], bf[j], acc[i][j], 0, 0, 0);
    }
  }

  const int q4 = g * 4;
#pragma unroll
  for (int i = 0; i < 4; i++)
#pragma unroll
    for (int j = 0; j < JT; j++) {
      const int mbase = m0 + wr + i * 16 + q4;
      const int n = n0 + wc + j * 16 + l16;
      float vals[4];
#pragma unroll
      for (int v = 0; v < 4; v++) vals[v] = acc[i][j][v] + bias[n];
      if (mode == 1) {
#pragma unroll
        for (int v = 0; v < 4; v++)
          outF[(size_t)(mbase + v) * N + n] = vals[v];
      } else {
        const int which = n >> 10;
        const int rem = n & 1023;
        const int h = rem >> 6, dd = rem & 63;
        const int b = mbase >> 11, t = mbase & 2047;  // t..t+3 within same b
        if (which == 2) {
          uint2 uu;
          uu.x = pk_bf16(vals[0], vals[1]);
          uu.y = pk_bf16(vals[2], vals[3]);
          *(uint2*)&out2[((size_t)((b * Hn + h) * DHd + dd)) * Tseq + t] = uu;
        } else {
          unsigned short* dst = (which == 0) ? out0 : out1;
#pragma unroll
          for (int v = 0; v < 4; v++)
            dst[(size_t)((b * Hn + h) * Tseq + t + v) * DHd + dd] = f2bf(vals[v]);
        }
      }
    }
}

// ---------------- MFMA causal flash attention, double-buffered K/V ----------------
// grid (bh=32, tiles=32 heavy-first); block 256 = 4 waves; wave w owns 16 q-rows.
// Per chunk: prefetch c+1 globals -> regs, compute c from LDS buf c&1,
// ds_write prefetch -> buf (c+1)&1, ONE __syncthreads.
// S^T = MFMA(A=K, B=Q): col=q (l16), row=j (4g+v). exp2-domain softmax.
__global__ __launch_bounds__(256, 3) void attn_mfma(const unsigned short* __restrict__ Qb,
                                                    const unsigned short* __restrict__ Kb,
                                                    const unsigned short* __restrict__ Vtg,
                                                    unsigned short* __restrict__ O) {
  __shared__ unsigned short Ks[2][64 * 72];   // [j][d]
  __shared__ unsigned short Vs[2][64 * 72];   // [d][j]
  __shared__ unsigned short Ps[4][16 * 72];   // per-wave [q][j]

  const int tid  = threadIdx.x;
  const int lane = tid & 63;
  const int w    = tid >> 6;
  const int g    = lane >> 4;
  const int l16  = lane & 15;
  const int bh   = blockIdx.x;
  const int tile = (int)gridDim.y - 1 - (int)blockIdx.y;   // heavy blocks first
  const int q0w  = tile * 64 + w * 16;

  const unsigned short* Qp = Qb  + (size_t)bh * Tseq * DHd;
  const unsigned short* Kp = Kb  + (size_t)bh * Tseq * DHd;
  const unsigned short* Vp = Vtg + (size_t)bh * DHd * Tseq;

  bf16x8 qf[2];
#pragma unroll
  for (int ks = 0; ks < 2; ks++)
    qf[ks] = *(const bf16x8*)&Qp[(size_t)(q0w + l16) * DHd + ks * 32 + g * 8];

  f32x4 Oacc[4];
#pragma unroll
  for (int dt = 0; dt < 4; dt++)
#pragma unroll
    for (int v = 0; v < 4; v++) Oacc[dt][v] = 0.f;

  float mrow = -1e30f, lrow = 0.f;
  unsigned short* Pw = Ps[w];
  const int srow = tid >> 3;        // 0..31
  const int sg8  = (tid & 7) * 8;

  const unsigned short* Kg0 = Kp + (size_t)srow * DHd + sg8;
  const unsigned short* Kg1 = Kp + (size_t)(srow + 32) * DHd + sg8;
  const unsigned short* Vg0 = Vp + (size_t)srow * Tseq + sg8;
  const unsigned short* Vg1 = Vp + (size_t)(srow + 32) * Tseq + sg8;

  {
    uint4 k0 = *(const uint4*)Kg0;
    uint4 k1 = *(const uint4*)Kg1;
    uint4 v0 = *(const uint4*)Vg0;
    uint4 v1 = *(const uint4*)Vg1;
    *(uint4*)&Ks[0][srow * 72 + sg8]        = k0;
    *(uint4*)&Ks[0][(srow + 32) * 72 + sg8] = k1;
    *(uint4*)&Vs[0][srow * 72 + sg8]        = v0;
    *(uint4*)&Vs[0][(srow + 32) * 72 + sg8] = v1;
  }
  __syncthreads();

  for (int c = 0; c <= tile; c++) {
    const int cur = c & 1, nxt = cur ^ 1;
    const bool pref = (c < tile);
    uint4 pk0, pk1, pv0, pv1;
    if (pref) {
      const size_t ko = (size_t)(c + 1) * 64 * DHd;
      const int    vo = (c + 1) * 64;
      pk0 = *(const uint4*)(Kg0 + ko);
      pk1 = *(const uint4*)(Kg1 + ko);
      pv0 = *(const uint4*)(Vg0 + vo);
      pv1 = *(const uint4*)(Vg1 + vo);
    }

    f32x4 st[4];
#pragma unroll
    for (int mt = 0; mt < 4; mt++)
#pragma unroll
      for (int v = 0; v < 4; v++) st[mt][v] = 0.f;
#pragma unroll
    for (int ks = 0; ks < 2; ks++) {
      bf16x8 kf[4];
#pragma unroll
      for (int mt = 0; mt < 4; mt++)
        kf[mt] = *(const bf16x8*)&Ks[cur][(16 * mt + l16) * 72 + ks * 32 + g * 8];
#pragma unroll
      for (int mt = 0; mt < 4; mt++)
        st[mt] = __builtin_amdgcn_mfma_f32_16x16x32_bf16(kf[mt], qf[ks], st[mt], 0, 0, 0);
    }

    const float SC = 0.1803368801f;  // 0.125 * log2(e)
    float mx = -1e30f;
    if (c == tile) {  // wave-uniform: only diagonal chunk pays masking
      const int qg = q0w + l16;
#pragma unroll
      for (int mt = 0; mt < 4; mt++)
#pragma unroll
        for (int v = 0; v < 4; v++) {
          float s = st[mt][v] * SC;
          if ((c * 64 + 16 * mt + 4 * g + v) > qg) s = -1e30f;
          st[mt][v] = s;
          mx = fmaxf(mx, s);
        }
    } else {
#pragma unroll
      for (int mt = 0; mt < 4; mt++)
#pragma unroll
        for (int v = 0; v < 4; v++) {
          float s = st[mt][v] * SC;
          st[mt][v] = s;
          mx = fmaxf(mx, s);
        }
    }
    mx = fmaxf(mx, __shfl_xor(mx, 16));
    mx = fmaxf(mx, __shfl_xor(mx, 32));
    const float mn = fmaxf(mrow, mx);
    const float alpha = __builtin_exp2f(mrow - mn);
    mrow = mn;
    float psum = 0.f;
#pragma unroll
    for (int mt = 0; mt < 4; mt++) {
      float p[4];
#pragma unroll
      for (int v = 0; v < 4; v++) { p[v] = __builtin_exp2f(st[mt][v] - mn); psum += p[v]; }
      uint2 uu;
      uu.x = pk_bf16(p[0], p[1]);
      uu.y = pk_bf16(p[2], p[3]);
      *(uint2*)&Pw[l16 * 72 + 16 * mt + 4 * g] = uu;
    }
    psum += __shfl_xor(psum, 16);
    psum += __shfl_xor(psum, 32);
    lrow = lrow * alpha + psum;

    const float a0 = __shfl(alpha, 4 * g + 0);
    const float a1 = __shfl(alpha, 4 * g + 1);
    const float a2 = __shfl(alpha, 4 * g + 2);
    const float a3 = __shfl(alpha, 4 * g + 3);
#pragma unroll
    for (int dt = 0; dt < 4; dt++) {
      Oacc[dt][0] *= a0;
      Oacc[dt][1] *= a1;
      Oacc[dt][2] *= a2;
      Oacc[dt][3] *= a3;
    }

#pragma unroll
    for (int ks = 0; ks < 2; ks++) {
      bf16x8 pf = *(const bf16x8*)&Pw[l16 * 72 + ks * 32 + g * 8];
      bf16x8 vf[4];
#pragma unroll
      for (int dt = 0; dt < 4; dt++)
        vf[dt] = *(const bf16x8*)&Vs[cur][(16 * dt + l16) * 72 + ks * 32 + g * 8];
#pragma unroll
      for (int dt = 0; dt < 4; dt++)
        Oacc[dt] = __builtin_amdgcn_mfma_f32_16x16x32_bf16(pf, vf[dt], Oacc[dt], 0, 0, 0);
    }

    if (pref) {
      *(uint4*)&Ks[nxt][srow * 72 + sg8]        = pk0;
      *(uint4*)&Ks[nxt][(srow + 32) * 72 + sg8] = pk1;
      *(uint4*)&Vs[nxt][srow * 72 + sg8]        = pv0;
      *(uint4*)&Vs[nxt][(srow + 32) * 72 + sg8] = pv1;
      __syncthreads();
    }
  }

  const float l0 = __shfl(lrow, 4 * g + 0);
  const float l1 = __shfl(lrow, 4 * g + 1);
  const float l2 = __shfl(lrow, 4 * g + 2);
  const float l3 = __shfl(lrow, 4 * g + 3);
  const float i0 = 1.f / l0, i1 = 1.f / l1, i2 = 1.f / l2, i3 = 1.f / l3;
  const int b = bh >> 4, h = bh & 15;
#pragma unroll
  for (int dt = 0; dt < 4; dt++) {
    const int d = h * DHd + 16 * dt + l16;
    const size_t r0 = (size_t)(b * Tseq + q0w + 4 * g) * Dmod + d;
    O[r0]            = f2bf(Oacc[dt][0] * i0);
    O[r0 + Dmod]     = f2bf(Oacc[dt][1] * i1);
    O[r0 + 2 * Dmod] = f2bf(Oacc[dt][2] * i2);
    O[r0 + 3 * Dmod] = f2bf(Oacc[dt][3] * i3);
  }
}

extern "C" void kernel_launch(void* const* d_in, const int* in_sizes, int n_in,
                              void* d_out, int out_size, void* d_ws, size_t ws_size,
                              hipStream_t stream) {
  (void)in_sizes; (void)n_in; (void)out_size; (void)ws_size;
  const float* x     = (const float*)d_in[0];  // [B,T,D]   fp32
  const float* w_qkv = (const float*)d_in[1];  // [D,3D]    fp32
  const float* b_qkv = (const float*)d_in[2];  // [3D]      fp32
  const float* w_out = (const float*)d_in[3];  // [D,D]     fp32
  const float* b_out = (const float*)d_in[4];  // [D]       fp32
  float* out = (float*)d_out;                  // [B,T,D]   fp32

  unsigned short* ws    = (unsigned short*)d_ws;
  unsigned short* xb    = ws;                            // [B*T, D] bf16, reused as Ob
  unsigned short* wqkvT = xb    + (size_t)4194304;       // [3D][D]
  unsigned short* woutT = wqkvT + (size_t)3072 * 1024;   // [D][D]
  unsigned short* Qb    = woutT + (size_t)1024 * 1024;   // [B,H,T,DH]
  unsigned short* Kb    = Qb + (size_t)4194304;          // [B,H,T,DH]
  unsigned short* Vt    = Kb + (size_t)4194304;          // [B,H,DH,T] (transposed)
  unsigned short* Ob    = xb;  // reuse: xb dead after GEMM1

  prep<<<3072, 256, 0, stream>>>(x, w_qkv, w_out, xb, wqkvT, woutT);
  gemm_bt<128><<<dim3(32, 24), 256, 0, stream>>>(xb, wqkvT, b_qkv, 4096, 3072, 1024, 0,
                                                 nullptr, Qb, Kb, Vt);
  attn_mfma<<<dim3(32, 32), 256, 0, stream>>>(Qb, Kb, Vt, Ob);
  gemm_bt<64><<<dim3(32, 16), 256, 0, stream>>>(Ob, woutT, b_out, 4096, 1024, 1024, 1,
                                                out, nullptr, nullptr, nullptr);
}